// Round 10
// baseline (673.972 us; speedup 1.0000x reference)
//
#include <hip/hip_runtime.h>
#include <hip/hip_bf16.h>
#include <math.h>

// Problem constants (fixed by setup_inputs)
constexpr int B = 256, P = 200, N = 200, E = 128, H = 8, D = 16;
constexpr float INV_SQRT_D = 0.25f;              // 1/sqrt(16)
constexpr float INV_SQRT_E = 0.08838834764831845f; // 1/sqrt(128)
constexpr float LOGIT_CLIP = 10.0f;
constexpr float INV_TEMP = 1.25f;                // 1/0.8
constexpr int TOP_K = 20;
constexpr int MAX_DELTA = 4;

__device__ __forceinline__ float dot4(float4 a, float4 b) {
    return a.x*b.x + a.y*b.y + a.z*b.z + a.w*b.w;
}

// ---------------------------------------------------------------------------
// GEMM: out[M,128] = X1[M,128] @ W1[128,128] (+ X2 @ W2) (+ bias)
// 32 rows/block, W in LDS K-chunks of 16 with register-prefetch dbuf.
// (used for mh = ao @ Wc + bc)
// ---------------------------------------------------------------------------
__global__ __launch_bounds__(256) void proj_kernel(
    const float* __restrict__ X1, const float* __restrict__ W1,
    const float* __restrict__ X2, const float* __restrict__ W2,
    const float* __restrict__ bias, float* __restrict__ out)
{
    __shared__ float4 xs[32][32];       // 32 rows x 128 floats (16 KB)
    __shared__ float4 ws[2][16][32];    // 16 k-rows x 128 floats, dbuf (16 KB)
    const int tid = threadIdx.x;
    const int eg = tid & 31;            // col group: cols eg*4..eg*4+3
    const int rg = tid >> 5;            // 0..7; rows rg + 8*i
    const long base = (long)blockIdx.x * 32;

    float acc[4][4];
    #pragma unroll
    for (int i = 0; i < 4; ++i)
        #pragma unroll
        for (int j = 0; j < 4; ++j) acc[i][j] = 0.f;

    for (int pass = 0; pass < 2; ++pass) {
        const float* X = pass ? X2 : X1;
        const float* W = pass ? W2 : W1;
        if (!X) break;
        if (pass) __syncthreads();
        const float4* X4 = (const float4*)X;
        const float4* W4 = (const float4*)W;
        #pragma unroll
        for (int t = 0; t < 4; ++t) {
            int idx = tid + 256 * t;
            int r = idx >> 5, c = idx & 31;
            xs[r][c] = X4[(base + r) * 32 + c];
        }
        #pragma unroll
        for (int t = 0; t < 2; ++t) {
            int idx = tid + 256 * t;
            int r = idx >> 5, c = idx & 31;
            ws[0][r][c] = W4[r * 32 + c];
        }
        __syncthreads();

        for (int kc = 0; kc < 8; ++kc) {
            const int cur = kc & 1;
            float4 pf0, pf1;
            if (kc < 7) {
                int i0 = tid, i1 = tid + 256;
                pf0 = W4[((kc + 1) * 16 + (i0 >> 5)) * 32 + (i0 & 31)];
                pf1 = W4[((kc + 1) * 16 + (i1 >> 5)) * 32 + (i1 & 31)];
            }
            #pragma unroll
            for (int k4 = 0; k4 < 4; ++k4) {
                float4 xv[4];
                #pragma unroll
                for (int i = 0; i < 4; ++i)
                    xv[i] = xs[rg + 8 * i][kc * 4 + k4];
                float4 w0 = ws[cur][k4 * 4 + 0][eg];
                float4 w1 = ws[cur][k4 * 4 + 1][eg];
                float4 w2 = ws[cur][k4 * 4 + 2][eg];
                float4 w3 = ws[cur][k4 * 4 + 3][eg];
                #pragma unroll
                for (int i = 0; i < 4; ++i) {
                    acc[i][0] += xv[i].x*w0.x + xv[i].y*w1.x + xv[i].z*w2.x + xv[i].w*w3.x;
                    acc[i][1] += xv[i].x*w0.y + xv[i].y*w1.y + xv[i].z*w2.y + xv[i].w*w3.y;
                    acc[i][2] += xv[i].x*w0.z + xv[i].y*w1.z + xv[i].z*w2.z + xv[i].w*w3.z;
                    acc[i][3] += xv[i].x*w0.w + xv[i].y*w1.w + xv[i].z*w2.w + xv[i].w*w3.w;
                }
            }
            if (kc < 7) {
                int i0 = tid, i1 = tid + 256;
                ws[cur ^ 1][i0 >> 5][i0 & 31] = pf0;
                ws[cur ^ 1][i1 >> 5][i1 & 31] = pf1;
                __syncthreads();
            }
        }
    }

    float4 bv = make_float4(0.f, 0.f, 0.f, 0.f);
    if (bias) bv = *(const float4*)&bias[eg * 4];
    float4* out4 = (float4*)out;
    #pragma unroll
    for (int i = 0; i < 4; ++i) {
        out4[(base + rg + 8 * i) * 32 + eg] =
            make_float4(acc[i][0]+bv.x, acc[i][1]+bv.y, acc[i][2]+bv.z, acc[i][3]+bv.w);
    }
}

// ---------------------------------------------------------------------------
// Merged q + kv projection in ONE dispatch (blocks 0..1599 = q, 1600..3199 =
// kv). Independent work co-schedules: one grid's tail fills the other's ramp,
// and one dispatch boundary disappears. Union LDS (48 KB max of both paths).
// ---------------------------------------------------------------------------
__global__ __launch_bounds__(256) void qkv_proj_kernel(
    const float* __restrict__ first, const float* __restrict__ Wqf,
    const float* __restrict__ last,  const float* __restrict__ Wql,
    float* __restrict__ outQ,
    const float* __restrict__ nodes, const float* __restrict__ Wk,
    const float* __restrict__ Wv, float* __restrict__ outK,
    float* __restrict__ outV)
{
    __shared__ float4 smem[3072];       // 48 KB union
    const int tid = threadIdx.x;
    const int eg = tid & 31;
    const int rg = tid >> 5;

    if (blockIdx.x < 1600) {
        // ----- q = first@Wqf + last@Wql -----
        const long base = (long)blockIdx.x * 32;
        float4 (*xs)[32]       = (float4 (*)[32])smem;              // [32][32]
        float4 (*wsb)[16][32]  = (float4 (*)[16][32])(smem + 1024); // [2][16][32]

        float acc[4][4];
        #pragma unroll
        for (int i = 0; i < 4; ++i)
            #pragma unroll
            for (int j = 0; j < 4; ++j) acc[i][j] = 0.f;

        for (int pass = 0; pass < 2; ++pass) {
            const float* X = pass ? last : first;
            const float* W = pass ? Wql : Wqf;
            if (pass) __syncthreads();
            const float4* X4 = (const float4*)X;
            const float4* W4 = (const float4*)W;
            #pragma unroll
            for (int t = 0; t < 4; ++t) {
                int idx = tid + 256 * t;
                xs[idx >> 5][idx & 31] = X4[(base + (idx >> 5)) * 32 + (idx & 31)];
            }
            #pragma unroll
            for (int t = 0; t < 2; ++t) {
                int idx = tid + 256 * t;
                wsb[0][idx >> 5][idx & 31] = W4[(idx >> 5) * 32 + (idx & 31)];
            }
            __syncthreads();

            for (int kc = 0; kc < 8; ++kc) {
                const int cur = kc & 1;
                float4 pf0, pf1;
                if (kc < 7) {
                    int i0 = tid, i1 = tid + 256;
                    pf0 = W4[((kc + 1) * 16 + (i0 >> 5)) * 32 + (i0 & 31)];
                    pf1 = W4[((kc + 1) * 16 + (i1 >> 5)) * 32 + (i1 & 31)];
                }
                #pragma unroll
                for (int k4 = 0; k4 < 4; ++k4) {
                    float4 xv[4];
                    #pragma unroll
                    for (int i = 0; i < 4; ++i)
                        xv[i] = xs[rg + 8 * i][kc * 4 + k4];
                    float4 w0 = wsb[cur][k4 * 4 + 0][eg];
                    float4 w1 = wsb[cur][k4 * 4 + 1][eg];
                    float4 w2 = wsb[cur][k4 * 4 + 2][eg];
                    float4 w3 = wsb[cur][k4 * 4 + 3][eg];
                    #pragma unroll
                    for (int i = 0; i < 4; ++i) {
                        acc[i][0] += xv[i].x*w0.x + xv[i].y*w1.x + xv[i].z*w2.x + xv[i].w*w3.x;
                        acc[i][1] += xv[i].x*w0.y + xv[i].y*w1.y + xv[i].z*w2.y + xv[i].w*w3.y;
                        acc[i][2] += xv[i].x*w0.z + xv[i].y*w1.z + xv[i].z*w2.z + xv[i].w*w3.z;
                        acc[i][3] += xv[i].x*w0.w + xv[i].y*w1.w + xv[i].z*w2.w + xv[i].w*w3.w;
                    }
                }
                if (kc < 7) {
                    int i0 = tid, i1 = tid + 256;
                    wsb[cur ^ 1][i0 >> 5][i0 & 31] = pf0;
                    wsb[cur ^ 1][i1 >> 5][i1 & 31] = pf1;
                    __syncthreads();
                }
            }
        }
        float4* out4 = (float4*)outQ;
        #pragma unroll
        for (int i = 0; i < 4; ++i)
            out4[(base + rg + 8 * i) * 32 + eg] =
                make_float4(acc[i][0], acc[i][1], acc[i][2], acc[i][3]);
    } else {
        // ----- k = nodes@Wk, v = nodes@Wv -----
        const long base = (long)(blockIdx.x - 1600) * 32;
        float4 (*xs)[32]      = (float4 (*)[32])smem;
        float4 (*wsk)[16][32] = (float4 (*)[16][32])(smem + 1024);
        float4 (*wsv)[16][32] = (float4 (*)[16][32])(smem + 2048);

        float acck[4][4], accv[4][4];
        #pragma unroll
        for (int i = 0; i < 4; ++i)
            #pragma unroll
            for (int j = 0; j < 4; ++j) { acck[i][j] = 0.f; accv[i][j] = 0.f; }

        const float4* X4  = (const float4*)nodes;
        const float4* Wk4 = (const float4*)Wk;
        const float4* Wv4 = (const float4*)Wv;
        #pragma unroll
        for (int t = 0; t < 4; ++t) {
            int idx = tid + 256 * t;
            xs[idx >> 5][idx & 31] = X4[(base + (idx >> 5)) * 32 + (idx & 31)];
        }
        #pragma unroll
        for (int t = 0; t < 2; ++t) {
            int idx = tid + 256 * t;
            wsk[0][idx >> 5][idx & 31] = Wk4[(idx >> 5) * 32 + (idx & 31)];
            wsv[0][idx >> 5][idx & 31] = Wv4[(idx >> 5) * 32 + (idx & 31)];
        }
        __syncthreads();

        for (int kc = 0; kc < 8; ++kc) {
            const int cur = kc & 1;
            float4 pk0, pk1, pv0, pv1;
            if (kc < 7) {
                int i0 = tid, i1 = tid + 256;
                int a0 = ((kc + 1) * 16 + (i0 >> 5)) * 32 + (i0 & 31);
                int a1 = ((kc + 1) * 16 + (i1 >> 5)) * 32 + (i1 & 31);
                pk0 = Wk4[a0]; pk1 = Wk4[a1];
                pv0 = Wv4[a0]; pv1 = Wv4[a1];
            }
            #pragma unroll
            for (int k4 = 0; k4 < 4; ++k4) {
                float4 xv[4];
                #pragma unroll
                for (int i = 0; i < 4; ++i)
                    xv[i] = xs[rg + 8 * i][kc * 4 + k4];
                float4 k0 = wsk[cur][k4 * 4 + 0][eg];
                float4 k1 = wsk[cur][k4 * 4 + 1][eg];
                float4 k2 = wsk[cur][k4 * 4 + 2][eg];
                float4 k3 = wsk[cur][k4 * 4 + 3][eg];
                float4 v0 = wsv[cur][k4 * 4 + 0][eg];
                float4 v1 = wsv[cur][k4 * 4 + 1][eg];
                float4 v2 = wsv[cur][k4 * 4 + 2][eg];
                float4 v3 = wsv[cur][k4 * 4 + 3][eg];
                #pragma unroll
                for (int i = 0; i < 4; ++i) {
                    acck[i][0] += xv[i].x*k0.x + xv[i].y*k1.x + xv[i].z*k2.x + xv[i].w*k3.x;
                    acck[i][1] += xv[i].x*k0.y + xv[i].y*k1.y + xv[i].z*k2.y + xv[i].w*k3.y;
                    acck[i][2] += xv[i].x*k0.z + xv[i].y*k1.z + xv[i].z*k2.z + xv[i].w*k3.z;
                    acck[i][3] += xv[i].x*k0.w + xv[i].y*k1.w + xv[i].z*k2.w + xv[i].w*k3.w;
                    accv[i][0] += xv[i].x*v0.x + xv[i].y*v1.x + xv[i].z*v2.x + xv[i].w*v3.x;
                    accv[i][1] += xv[i].x*v0.y + xv[i].y*v1.y + xv[i].z*v2.y + xv[i].w*v3.y;
                    accv[i][2] += xv[i].x*v0.z + xv[i].y*v1.z + xv[i].z*v2.z + xv[i].w*v3.z;
                    accv[i][3] += xv[i].x*v0.w + xv[i].y*v1.w + xv[i].z*v2.w + xv[i].w*v3.w;
                }
            }
            if (kc < 7) {
                int i0 = tid, i1 = tid + 256;
                wsk[cur ^ 1][i0 >> 5][i0 & 31] = pk0;
                wsk[cur ^ 1][i1 >> 5][i1 & 31] = pk1;
                wsv[cur ^ 1][i0 >> 5][i0 & 31] = pv0;
                wsv[cur ^ 1][i1 >> 5][i1 & 31] = pv1;
                __syncthreads();
            }
        }

        float4* outK4 = (float4*)outK;
        float4* outV4 = (float4*)outV;
        #pragma unroll
        for (int i = 0; i < 4; ++i) {
            outK4[(base + rg + 8 * i) * 32 + eg] =
                make_float4(acck[i][0], acck[i][1], acck[i][2], acck[i][3]);
            outV4[(base + rg + 8 * i) * 32 + eg] =
                make_float4(accv[i][0], accv[i][1], accv[i][2], accv[i][3]);
        }
    }
}

// ---------------------------------------------------------------------------
// Attention: bound-softmax single pass (unchanged from R6/R8).
// ---------------------------------------------------------------------------
__global__ __launch_bounds__(256) void attn_kernel(
    const float* __restrict__ q, const float* __restrict__ k,
    const float* __restrict__ v, const float* __restrict__ mask,
    float* __restrict__ out)
{
    __shared__ float4 ks[N][4];
    __shared__ float4 vs[N][4];
    __shared__ float red[4];
    const int raw = blockIdx.x;
    const int g = raw >> 6, rr6 = raw & 63;
    const int h = rr6 >> 3;
    const int b = g * 8 + (rr6 & 7);
    const int tid = threadIdx.x;

    const float4* k4 = (const float4*)k;
    const float4* v4 = (const float4*)v;
    for (int idx = tid; idx < N * 4; idx += 256) {
        int n = idx >> 2, c = idx & 3;
        size_t off = (size_t)(b * N + n) * 32 + h * 4 + c;
        ks[n][c] = k4[off];
        vs[n][c] = v4[off];
    }
    __syncthreads();

    float nrm = 0.f;
    if (tid < N) {
        float4 a0 = ks[tid][0], a1 = ks[tid][1], a2 = ks[tid][2], a3 = ks[tid][3];
        nrm = dot4(a0,a0) + dot4(a1,a1) + dot4(a2,a2) + dot4(a3,a3);
    }
    float wm = nrm;
    #pragma unroll
    for (int off = 32; off > 0; off >>= 1) wm = fmaxf(wm, __shfl_xor(wm, off));
    if ((tid & 63) == 0) red[tid >> 6] = wm;
    __syncthreads();
    const float kmax2 = fmaxf(fmaxf(red[0], red[1]), fmaxf(red[2], red[3]));

    const int p = tid;
    if (p >= P) return;

    const float4* qr = (const float4*)q + (size_t)(b * P + p) * 32 + h * 4;
    float4 q0 = qr[0], q1 = qr[1], q2 = qr[2], q3 = qr[3];
    q0.x*=INV_SQRT_D; q0.y*=INV_SQRT_D; q0.z*=INV_SQRT_D; q0.w*=INV_SQRT_D;
    q1.x*=INV_SQRT_D; q1.y*=INV_SQRT_D; q1.z*=INV_SQRT_D; q1.w*=INV_SQRT_D;
    q2.x*=INV_SQRT_D; q2.y*=INV_SQRT_D; q2.z*=INV_SQRT_D; q2.w*=INV_SQRT_D;
    q3.x*=INV_SQRT_D; q3.y*=INV_SQRT_D; q3.z*=INV_SQRT_D; q3.w*=INV_SQRT_D;
    const float qn2 = dot4(q0,q0) + dot4(q1,q1) + dot4(q2,q2) + dot4(q3,q3);
    const float M = sqrtf(qn2 * kmax2);

    const float4* m4 = (const float4*)(mask + (size_t)(b * P + p) * N);

    float l = 0.f;
    float o[16];
    #pragma unroll
    for (int d = 0; d < 16; ++d) o[d] = 0.f;

    #pragma unroll 2
    for (int n4 = 0; n4 < N / 4; ++n4) {
        float4 mv = m4[n4];
        float mvf[4] = {mv.x, mv.y, mv.z, mv.w};
        #pragma unroll
        for (int j = 0; j < 4; ++j) {
            int n = n4 * 4 + j;
            float s = dot4(q0, ks[n][0]) + dot4(q1, ks[n][1]) +
                      dot4(q2, ks[n][2]) + dot4(q3, ks[n][3]);
            float w = __expf(s + mvf[j] - M);
            l += w;
            float4 v0 = vs[n][0], v1 = vs[n][1], v2 = vs[n][2], v3 = vs[n][3];
            o[0]  += w*v0.x; o[1]  += w*v0.y; o[2]  += w*v0.z; o[3]  += w*v0.w;
            o[4]  += w*v1.x; o[5]  += w*v1.y; o[6]  += w*v1.z; o[7]  += w*v1.w;
            o[8]  += w*v2.x; o[9]  += w*v2.y; o[10] += w*v2.z; o[11] += w*v2.w;
            o[12] += w*v3.x; o[13] += w*v3.y; o[14] += w*v3.z; o[15] += w*v3.w;
        }
    }

    float inv_l = 1.f / l;
    float4* out4 = (float4*)out;
    size_t ob = (size_t)(b * P + p) * 32 + h * 4;
    #pragma unroll
    for (int c = 0; c < 4; ++c)
        out4[ob + c] = make_float4(o[c*4]*inv_l, o[c*4+1]*inv_l,
                                   o[c*4+2]*inv_l, o[c*4+3]*inv_l);
}

// ---------------------------------------------------------------------------
// Fused pointer + top-k. Block = (b, 64-row p-tile); computes the FULL
// 200-col logit strip into LDS, then radix-selects per row in-block.
// Kills the 82 MB logits round-trip and the separate topk dispatch.
// Phase 1: sc = mh @ nodes^T in n-chunks of 32 (nodes chunk in LDS, mh rows
//   from global/L1 — the 32 KB row-tile is L1-resident), fused
//   tanh/bias/mask epilogue into lg[64][225] (pad 225 -> phase-2 reads
//   conflict-free, phase-1 writes <=4-way on a tiny fraction of insts).
// Phase 2: per-wave radix-select (identical semantics to topk_kernel).
// XCD remap: 4 p-tiles of a b land on one XCD (nodes/mask L2 reuse).
// ---------------------------------------------------------------------------
__global__ __launch_bounds__(256) void pointer_topk_kernel(
    const float* __restrict__ mh, const float* __restrict__ nodes,
    const float* __restrict__ mask, const int* __restrict__ gid,
    const int* __restrict__ cmp, const float* __restrict__ btab,
    float* __restrict__ out)
{
    __shared__ float4 ns[32][33];     // nodes chunk: 32 rows x 128 f (16.9 KB)
    __shared__ float lg[64][225];     // logit strip (57.6 KB)

    // raw = g*32 + t*8 + bl ; b = g*8 + bl ; p0 = t*64  (raw%8 == b%8)
    const int raw = blockIdx.x;
    const int g = raw >> 5, r5 = raw & 31;
    const int t = r5 >> 3;
    const int b = g * 8 + (r5 & 7);
    const int p0 = t * 64;
    const int tid = threadIdx.x;
    const int pi = tid >> 4;          // 0..15
    const int ni = tid & 15;          // 0..15

    // hoist per-p and table data
    int cmv[4];
    #pragma unroll
    for (int i = 0; i < 4; ++i) {
        int p = p0 + pi + 16 * i;
        int pc = p < P ? p : P - 1;
        cmv[i] = cmp[b * P + pc];
    }
    float bt[MAX_DELTA + 1];
    #pragma unroll
    for (int tt = 0; tt <= MAX_DELTA; ++tt) bt[tt] = btab[tt];

    const float4* mh4 = (const float4*)mh;
    const float4* nodes4 = (const float4*)nodes;

    // ---- phase 1: logits ----
    for (int nc = 0; nc < 7; ++nc) {      // n-chunks of 32 (7*32=224 >= 200)
        const int n0 = nc * 32;
        if (nc) __syncthreads();          // ns reuse
        #pragma unroll
        for (int s = 0; s < 4; ++s) {
            int idx = tid + 256 * s;
            int rr = idx >> 5, cc = idx & 31;
            int nr = n0 + rr; nr = nr < N ? nr : N - 1;
            ns[rr][cc] = nodes4[(size_t)(b * N + nr) * 32 + cc];
        }
        __syncthreads();

        float acc[4][2];
        #pragma unroll
        for (int i = 0; i < 4; ++i) { acc[i][0] = 0.f; acc[i][1] = 0.f; }

        #pragma unroll 4
        for (int c4 = 0; c4 < 32; ++c4) {
            float4 a[4];
            #pragma unroll
            for (int i = 0; i < 4; ++i) {
                int p = p0 + pi + 16 * i;
                int pc = p < P ? p : P - 1;
                a[i] = mh4[(size_t)(b * P + pc) * 32 + c4];
            }
            float4 w0 = ns[ni][c4];
            float4 w1 = ns[ni + 16][c4];
            #pragma unroll
            for (int i = 0; i < 4; ++i) {
                acc[i][0] += dot4(a[i], w0);
                acc[i][1] += dot4(a[i], w1);
            }
        }

        // epilogue -> LDS logits
        #pragma unroll
        for (int jj = 0; jj < 2; ++jj) {
            int n = n0 + ni + 16 * jj;
            if (n >= N) continue;
            int gg = gid[b * N + n];
            #pragma unroll
            for (int i = 0; i < 4; ++i) {
                int p = p0 + pi + 16 * i;
                int pc = p < P ? p : P - 1;
                int delta = gg - cmv[i];
                delta = delta < 0 ? 0 : (delta > MAX_DELTA ? MAX_DELTA : delta);
                float mv = mask[(size_t)(b * P + pc) * N + n];
                float pb = isfinite(mv) ? bt[delta] : 0.f;
                // 10*tanh(x) = 10 - 20/(exp(2x)+1)
                float ex = __expf(2.f * acc[i][jj] * INV_SQRT_E);
                float logit = LOGIT_CLIP - 20.f / (ex + 1.f) + pb + mv;
                lg[pi + 16 * i][n] = logit;
            }
        }
    }
    __syncthreads();

    // ---- phase 2: per-row radix-select top-20 + temperature + renorm ----
    const int wv = tid >> 6, lane = tid & 63;
    const unsigned long long lt_mask = (1ull << lane) - 1ull;
    for (int rr = 0; rr < 16; ++rr) {
        int row = wv * 16 + rr;
        int p = p0 + row;
        if (p >= P) break;                 // wave-uniform

        float x[4];
        unsigned u[4];
        #pragma unroll
        for (int j = 0; j < 4; ++j) {
            int n = lane + 64 * j;
            bool valid = n < N;
            x[j] = valid ? lg[row][n] : -INFINITY;
            unsigned bb = __float_as_uint(x[j]);
            u[j] = valid ? ((bb & 0x80000000u) ? ~bb : (bb | 0x80000000u)) : 0u;
        }

        unsigned pth = 0;
        for (int i = 31; i >= 0; --i) {
            unsigned c = pth | (1u << i);
            int cnt = 0;
            #pragma unroll
            for (int j = 0; j < 4; ++j)
                cnt += (int)__popcll(__ballot(u[j] >= c));
            if (cnt >= TOP_K) pth = c;
        }

        int cnt_gt = 0;
        #pragma unroll
        for (int j = 0; j < 4; ++j)
            cnt_gt += (int)__popcll(__ballot(u[j] > pth));
        const int needed = TOP_K - cnt_gt;

        bool sel[4];
        int eq_before = 0;
        #pragma unroll
        for (int j = 0; j < 4; ++j) {
            unsigned long long em = __ballot(u[j] == pth);
            int myrank = eq_before + (int)__popcll(em & lt_mask);
            sel[j] = (u[j] > pth) || ((u[j] == pth) && (myrank < needed));
            eq_before += (int)__popcll(em);
        }

        unsigned tb = (pth & 0x80000000u) ? (pth & 0x7FFFFFFFu) : ~pth;
        float Tf = __uint_as_float(tb);

        float e[4];
        float sum = 0.f;
        if (isfinite(Tf)) {
            #pragma unroll
            for (int j = 0; j < 4; ++j) {
                e[j] = sel[j] ? __expf((x[j] - Tf) * INV_TEMP) : 0.f;
                sum += e[j];
            }
        } else {
            #pragma unroll
            for (int j = 0; j < 4; ++j) {
                e[j] = sel[j] ? 1.f : 0.f;
                sum += e[j];
            }
        }
        #pragma unroll
        for (int off = 32; off > 0; off >>= 1) sum += __shfl_xor(sum, off);
        float inv = 1.f / sum;
        float* orow = out + (size_t)(b * P + p) * N;
        #pragma unroll
        for (int j = 0; j < 4; ++j) {
            int n = lane + 64 * j;
            if (n < N) orow[n] = e[j] * inv;
        }
    }
}

// ---------------------------------------------------------------------------
extern "C" void kernel_launch(void* const* d_in, const int* in_sizes, int n_in,
                              void* d_out, int out_size, void* d_ws, size_t ws_size,
                              hipStream_t stream) {
    const float* nodes = (const float*)d_in[0];
    const float* first = (const float*)d_in[1];
    const float* last  = (const float*)d_in[2];
    const float* mask  = (const float*)d_in[3];
    const int*   gid   = (const int*)d_in[4];
    const int*   cmp   = (const int*)d_in[5];
    const float* Wqf   = (const float*)d_in[6];
    const float* Wql   = (const float*)d_in[7];
    const float* Wk    = (const float*)d_in[8];
    const float* Wv    = (const float*)d_in[9];
    const float* Wc    = (const float*)d_in[10];
    const float* bc    = (const float*)d_in[11];
    const float* btab  = (const float*)d_in[12];
    float* out = (float*)d_out;

    float* ws   = (float*)d_ws;
    const size_t SLOT = (size_t)B * P * E;   // 6,553,600 floats
    float* qb  = ws;                 // q, later reused for mh
    float* kb  = ws + SLOT;
    float* vb  = ws + 2 * SLOT;
    float* ao  = ws + 3 * SLOT;      // attention output (concat heads)

    const int M = B * P;             // 51200 rows (= B*N too)

    // q, k, v in one dispatch (blocks 0..1599 -> q, 1600..3199 -> k/v)
    qkv_proj_kernel<<<2 * (M / 32), 256, 0, stream>>>(
        first, Wqf, last, Wql, qb, nodes, Wk, Wv, kb, vb);

    // masked MHA (bound-softmax single pass, XCD-aware remap)
    attn_kernel<<<B * H, 256, 0, stream>>>(qb, kb, vb, mask, ao);

    // mh = ao @ Wc + bc   (into q's slot — q is dead now)
    proj_kernel<<<M / 32, 256, 0, stream>>>(ao, Wc, nullptr, nullptr, bc, qb);

    // pointer logits + top-k + renormalize, fused, straight into d_out
    pointer_topk_kernel<<<B * 4, 256, 0, stream>>>(
        qb, nodes, mask, gid, cmp, btab, out);
}

// Round 11
// 583.028 us; speedup vs baseline: 1.1560x; 1.1560x over previous
//
#include <hip/hip_runtime.h>
#include <hip/hip_bf16.h>
#include <math.h>

// Problem constants (fixed by setup_inputs)
constexpr int B = 256, P = 200, N = 200, E = 128, H = 8, D = 16;
constexpr float INV_SQRT_D = 0.25f;              // 1/sqrt(16)
constexpr float INV_SQRT_E = 0.08838834764831845f; // 1/sqrt(128)
constexpr float LOGIT_CLIP = 10.0f;
constexpr float INV_TEMP = 1.25f;                // 1/0.8
constexpr int TOP_K = 20;
constexpr int MAX_DELTA = 4;

__device__ __forceinline__ float dot4(float4 a, float4 b) {
    return a.x*b.x + a.y*b.y + a.z*b.z + a.w*b.w;
}

// ---------------------------------------------------------------------------
// GEMM: out[M,128] = X1[M,128] @ W1[128,128] (+ X2 @ W2) (+ bias)
// 32 rows/block, W in LDS K-chunks of 16 with register-prefetch dbuf.
// (used for mh = ao @ Wc + bc)
// ---------------------------------------------------------------------------
__global__ __launch_bounds__(256) void proj_kernel(
    const float* __restrict__ X1, const float* __restrict__ W1,
    const float* __restrict__ X2, const float* __restrict__ W2,
    const float* __restrict__ bias, float* __restrict__ out)
{
    __shared__ float4 xs[32][32];       // 32 rows x 128 floats (16 KB)
    __shared__ float4 ws[2][16][32];    // 16 k-rows x 128 floats, dbuf (16 KB)
    const int tid = threadIdx.x;
    const int eg = tid & 31;            // col group: cols eg*4..eg*4+3
    const int rg = tid >> 5;            // 0..7; rows rg + 8*i
    const long base = (long)blockIdx.x * 32;

    float acc[4][4];
    #pragma unroll
    for (int i = 0; i < 4; ++i)
        #pragma unroll
        for (int j = 0; j < 4; ++j) acc[i][j] = 0.f;

    for (int pass = 0; pass < 2; ++pass) {
        const float* X = pass ? X2 : X1;
        const float* W = pass ? W2 : W1;
        if (!X) break;
        if (pass) __syncthreads();
        const float4* X4 = (const float4*)X;
        const float4* W4 = (const float4*)W;
        #pragma unroll
        for (int t = 0; t < 4; ++t) {
            int idx = tid + 256 * t;
            int r = idx >> 5, c = idx & 31;
            xs[r][c] = X4[(base + r) * 32 + c];
        }
        #pragma unroll
        for (int t = 0; t < 2; ++t) {
            int idx = tid + 256 * t;
            int r = idx >> 5, c = idx & 31;
            ws[0][r][c] = W4[r * 32 + c];
        }
        __syncthreads();

        for (int kc = 0; kc < 8; ++kc) {
            const int cur = kc & 1;
            float4 pf0, pf1;
            if (kc < 7) {
                int i0 = tid, i1 = tid + 256;
                pf0 = W4[((kc + 1) * 16 + (i0 >> 5)) * 32 + (i0 & 31)];
                pf1 = W4[((kc + 1) * 16 + (i1 >> 5)) * 32 + (i1 & 31)];
            }
            #pragma unroll
            for (int k4 = 0; k4 < 4; ++k4) {
                float4 xv[4];
                #pragma unroll
                for (int i = 0; i < 4; ++i)
                    xv[i] = xs[rg + 8 * i][kc * 4 + k4];
                float4 w0 = ws[cur][k4 * 4 + 0][eg];
                float4 w1 = ws[cur][k4 * 4 + 1][eg];
                float4 w2 = ws[cur][k4 * 4 + 2][eg];
                float4 w3 = ws[cur][k4 * 4 + 3][eg];
                #pragma unroll
                for (int i = 0; i < 4; ++i) {
                    acc[i][0] += xv[i].x*w0.x + xv[i].y*w1.x + xv[i].z*w2.x + xv[i].w*w3.x;
                    acc[i][1] += xv[i].x*w0.y + xv[i].y*w1.y + xv[i].z*w2.y + xv[i].w*w3.y;
                    acc[i][2] += xv[i].x*w0.z + xv[i].y*w1.z + xv[i].z*w2.z + xv[i].w*w3.z;
                    acc[i][3] += xv[i].x*w0.w + xv[i].y*w1.w + xv[i].z*w2.w + xv[i].w*w3.w;
                }
            }
            if (kc < 7) {
                int i0 = tid, i1 = tid + 256;
                ws[cur ^ 1][i0 >> 5][i0 & 31] = pf0;
                ws[cur ^ 1][i1 >> 5][i1 & 31] = pf1;
                __syncthreads();
            }
        }
    }

    float4 bv = make_float4(0.f, 0.f, 0.f, 0.f);
    if (bias) bv = *(const float4*)&bias[eg * 4];
    float4* out4 = (float4*)out;
    #pragma unroll
    for (int i = 0; i < 4; ++i) {
        out4[(base + rg + 8 * i) * 32 + eg] =
            make_float4(acc[i][0]+bv.x, acc[i][1]+bv.y, acc[i][2]+bv.z, acc[i][3]+bv.w);
    }
}

// ---------------------------------------------------------------------------
// Merged q + kv projection in ONE dispatch (blocks 0..1599 = q, 1600..3199 =
// kv). Independent work co-schedules: one grid's tail fills the other's ramp.
// ---------------------------------------------------------------------------
__global__ __launch_bounds__(256) void qkv_proj_kernel(
    const float* __restrict__ first, const float* __restrict__ Wqf,
    const float* __restrict__ last,  const float* __restrict__ Wql,
    float* __restrict__ outQ,
    const float* __restrict__ nodes, const float* __restrict__ Wk,
    const float* __restrict__ Wv, float* __restrict__ outK,
    float* __restrict__ outV)
{
    __shared__ float4 smem[3072];       // 48 KB union
    const int tid = threadIdx.x;
    const int eg = tid & 31;
    const int rg = tid >> 5;

    if (blockIdx.x < 1600) {
        // ----- q = first@Wqf + last@Wql -----
        const long base = (long)blockIdx.x * 32;
        float4 (*xs)[32]       = (float4 (*)[32])smem;              // [32][32]
        float4 (*wsb)[16][32]  = (float4 (*)[16][32])(smem + 1024); // [2][16][32]

        float acc[4][4];
        #pragma unroll
        for (int i = 0; i < 4; ++i)
            #pragma unroll
            for (int j = 0; j < 4; ++j) acc[i][j] = 0.f;

        for (int pass = 0; pass < 2; ++pass) {
            const float* X = pass ? last : first;
            const float* W = pass ? Wql : Wqf;
            if (pass) __syncthreads();
            const float4* X4 = (const float4*)X;
            const float4* W4 = (const float4*)W;
            #pragma unroll
            for (int t = 0; t < 4; ++t) {
                int idx = tid + 256 * t;
                xs[idx >> 5][idx & 31] = X4[(base + (idx >> 5)) * 32 + (idx & 31)];
            }
            #pragma unroll
            for (int t = 0; t < 2; ++t) {
                int idx = tid + 256 * t;
                wsb[0][idx >> 5][idx & 31] = W4[(idx >> 5) * 32 + (idx & 31)];
            }
            __syncthreads();

            for (int kc = 0; kc < 8; ++kc) {
                const int cur = kc & 1;
                float4 pf0, pf1;
                if (kc < 7) {
                    int i0 = tid, i1 = tid + 256;
                    pf0 = W4[((kc + 1) * 16 + (i0 >> 5)) * 32 + (i0 & 31)];
                    pf1 = W4[((kc + 1) * 16 + (i1 >> 5)) * 32 + (i1 & 31)];
                }
                #pragma unroll
                for (int k4 = 0; k4 < 4; ++k4) {
                    float4 xv[4];
                    #pragma unroll
                    for (int i = 0; i < 4; ++i)
                        xv[i] = xs[rg + 8 * i][kc * 4 + k4];
                    float4 w0 = wsb[cur][k4 * 4 + 0][eg];
                    float4 w1 = wsb[cur][k4 * 4 + 1][eg];
                    float4 w2 = wsb[cur][k4 * 4 + 2][eg];
                    float4 w3 = wsb[cur][k4 * 4 + 3][eg];
                    #pragma unroll
                    for (int i = 0; i < 4; ++i) {
                        acc[i][0] += xv[i].x*w0.x + xv[i].y*w1.x + xv[i].z*w2.x + xv[i].w*w3.x;
                        acc[i][1] += xv[i].x*w0.y + xv[i].y*w1.y + xv[i].z*w2.y + xv[i].w*w3.y;
                        acc[i][2] += xv[i].x*w0.z + xv[i].y*w1.z + xv[i].z*w2.z + xv[i].w*w3.z;
                        acc[i][3] += xv[i].x*w0.w + xv[i].y*w1.w + xv[i].z*w2.w + xv[i].w*w3.w;
                    }
                }
                if (kc < 7) {
                    int i0 = tid, i1 = tid + 256;
                    wsb[cur ^ 1][i0 >> 5][i0 & 31] = pf0;
                    wsb[cur ^ 1][i1 >> 5][i1 & 31] = pf1;
                    __syncthreads();
                }
            }
        }
        float4* out4 = (float4*)outQ;
        #pragma unroll
        for (int i = 0; i < 4; ++i)
            out4[(base + rg + 8 * i) * 32 + eg] =
                make_float4(acc[i][0], acc[i][1], acc[i][2], acc[i][3]);
    } else {
        // ----- k = nodes@Wk, v = nodes@Wv -----
        const long base = (long)(blockIdx.x - 1600) * 32;
        float4 (*xs)[32]      = (float4 (*)[32])smem;
        float4 (*wsk)[16][32] = (float4 (*)[16][32])(smem + 1024);
        float4 (*wsv)[16][32] = (float4 (*)[16][32])(smem + 2048);

        float acck[4][4], accv[4][4];
        #pragma unroll
        for (int i = 0; i < 4; ++i)
            #pragma unroll
            for (int j = 0; j < 4; ++j) { acck[i][j] = 0.f; accv[i][j] = 0.f; }

        const float4* X4  = (const float4*)nodes;
        const float4* Wk4 = (const float4*)Wk;
        const float4* Wv4 = (const float4*)Wv;
        #pragma unroll
        for (int t = 0; t < 4; ++t) {
            int idx = tid + 256 * t;
            xs[idx >> 5][idx & 31] = X4[(base + (idx >> 5)) * 32 + (idx & 31)];
        }
        #pragma unroll
        for (int t = 0; t < 2; ++t) {
            int idx = tid + 256 * t;
            wsk[0][idx >> 5][idx & 31] = Wk4[(idx >> 5) * 32 + (idx & 31)];
            wsv[0][idx >> 5][idx & 31] = Wv4[(idx >> 5) * 32 + (idx & 31)];
        }
        __syncthreads();

        for (int kc = 0; kc < 8; ++kc) {
            const int cur = kc & 1;
            float4 pk0, pk1, pv0, pv1;
            if (kc < 7) {
                int i0 = tid, i1 = tid + 256;
                int a0 = ((kc + 1) * 16 + (i0 >> 5)) * 32 + (i0 & 31);
                int a1 = ((kc + 1) * 16 + (i1 >> 5)) * 32 + (i1 & 31);
                pk0 = Wk4[a0]; pk1 = Wk4[a1];
                pv0 = Wv4[a0]; pv1 = Wv4[a1];
            }
            #pragma unroll
            for (int k4 = 0; k4 < 4; ++k4) {
                float4 xv[4];
                #pragma unroll
                for (int i = 0; i < 4; ++i)
                    xv[i] = xs[rg + 8 * i][kc * 4 + k4];
                float4 k0 = wsk[cur][k4 * 4 + 0][eg];
                float4 k1 = wsk[cur][k4 * 4 + 1][eg];
                float4 k2 = wsk[cur][k4 * 4 + 2][eg];
                float4 k3 = wsk[cur][k4 * 4 + 3][eg];
                float4 v0 = wsv[cur][k4 * 4 + 0][eg];
                float4 v1 = wsv[cur][k4 * 4 + 1][eg];
                float4 v2 = wsv[cur][k4 * 4 + 2][eg];
                float4 v3 = wsv[cur][k4 * 4 + 3][eg];
                #pragma unroll
                for (int i = 0; i < 4; ++i) {
                    acck[i][0] += xv[i].x*k0.x + xv[i].y*k1.x + xv[i].z*k2.x + xv[i].w*k3.x;
                    acck[i][1] += xv[i].x*k0.y + xv[i].y*k1.y + xv[i].z*k2.y + xv[i].w*k3.y;
                    acck[i][2] += xv[i].x*k0.z + xv[i].y*k1.z + xv[i].z*k2.z + xv[i].w*k3.z;
                    acck[i][3] += xv[i].x*k0.w + xv[i].y*k1.w + xv[i].z*k2.w + xv[i].w*k3.w;
                    accv[i][0] += xv[i].x*v0.x + xv[i].y*v1.x + xv[i].z*v2.x + xv[i].w*v3.x;
                    accv[i][1] += xv[i].x*v0.y + xv[i].y*v1.y + xv[i].z*v2.y + xv[i].w*v3.y;
                    accv[i][2] += xv[i].x*v0.z + xv[i].y*v1.z + xv[i].z*v2.z + xv[i].w*v3.z;
                    accv[i][3] += xv[i].x*v0.w + xv[i].y*v1.w + xv[i].z*v2.w + xv[i].w*v3.w;
                }
            }
            if (kc < 7) {
                int i0 = tid, i1 = tid + 256;
                wsk[cur ^ 1][i0 >> 5][i0 & 31] = pk0;
                wsk[cur ^ 1][i1 >> 5][i1 & 31] = pk1;
                wsv[cur ^ 1][i0 >> 5][i0 & 31] = pv0;
                wsv[cur ^ 1][i1 >> 5][i1 & 31] = pv1;
                __syncthreads();
            }
        }

        float4* outK4 = (float4*)outK;
        float4* outV4 = (float4*)outV;
        #pragma unroll
        for (int i = 0; i < 4; ++i) {
            outK4[(base + rg + 8 * i) * 32 + eg] =
                make_float4(acck[i][0], acck[i][1], acck[i][2], acck[i][3]);
            outV4[(base + rg + 8 * i) * 32 + eg] =
                make_float4(accv[i][0], accv[i][1], accv[i][2], accv[i][3]);
        }
    }
}

// ---------------------------------------------------------------------------
// Attention: bound-softmax single pass (unchanged from R6/R8).
// ---------------------------------------------------------------------------
__global__ __launch_bounds__(256) void attn_kernel(
    const float* __restrict__ q, const float* __restrict__ k,
    const float* __restrict__ v, const float* __restrict__ mask,
    float* __restrict__ out)
{
    __shared__ float4 ks[N][4];
    __shared__ float4 vs[N][4];
    __shared__ float red[4];
    const int raw = blockIdx.x;
    const int g = raw >> 6, rr6 = raw & 63;
    const int h = rr6 >> 3;
    const int b = g * 8 + (rr6 & 7);
    const int tid = threadIdx.x;

    const float4* k4 = (const float4*)k;
    const float4* v4 = (const float4*)v;
    for (int idx = tid; idx < N * 4; idx += 256) {
        int n = idx >> 2, c = idx & 3;
        size_t off = (size_t)(b * N + n) * 32 + h * 4 + c;
        ks[n][c] = k4[off];
        vs[n][c] = v4[off];
    }
    __syncthreads();

    float nrm = 0.f;
    if (tid < N) {
        float4 a0 = ks[tid][0], a1 = ks[tid][1], a2 = ks[tid][2], a3 = ks[tid][3];
        nrm = dot4(a0,a0) + dot4(a1,a1) + dot4(a2,a2) + dot4(a3,a3);
    }
    float wm = nrm;
    #pragma unroll
    for (int off = 32; off > 0; off >>= 1) wm = fmaxf(wm, __shfl_xor(wm, off));
    if ((tid & 63) == 0) red[tid >> 6] = wm;
    __syncthreads();
    const float kmax2 = fmaxf(fmaxf(red[0], red[1]), fmaxf(red[2], red[3]));

    const int p = tid;
    if (p >= P) return;

    const float4* qr = (const float4*)q + (size_t)(b * P + p) * 32 + h * 4;
    float4 q0 = qr[0], q1 = qr[1], q2 = qr[2], q3 = qr[3];
    q0.x*=INV_SQRT_D; q0.y*=INV_SQRT_D; q0.z*=INV_SQRT_D; q0.w*=INV_SQRT_D;
    q1.x*=INV_SQRT_D; q1.y*=INV_SQRT_D; q1.z*=INV_SQRT_D; q1.w*=INV_SQRT_D;
    q2.x*=INV_SQRT_D; q2.y*=INV_SQRT_D; q2.z*=INV_SQRT_D; q2.w*=INV_SQRT_D;
    q3.x*=INV_SQRT_D; q3.y*=INV_SQRT_D; q3.z*=INV_SQRT_D; q3.w*=INV_SQRT_D;
    const float qn2 = dot4(q0,q0) + dot4(q1,q1) + dot4(q2,q2) + dot4(q3,q3);
    const float M = sqrtf(qn2 * kmax2);

    const float4* m4 = (const float4*)(mask + (size_t)(b * P + p) * N);

    float l = 0.f;
    float o[16];
    #pragma unroll
    for (int d = 0; d < 16; ++d) o[d] = 0.f;

    #pragma unroll 2
    for (int n4 = 0; n4 < N / 4; ++n4) {
        float4 mv = m4[n4];
        float mvf[4] = {mv.x, mv.y, mv.z, mv.w};
        #pragma unroll
        for (int j = 0; j < 4; ++j) {
            int n = n4 * 4 + j;
            float s = dot4(q0, ks[n][0]) + dot4(q1, ks[n][1]) +
                      dot4(q2, ks[n][2]) + dot4(q3, ks[n][3]);
            float w = __expf(s + mvf[j] - M);
            l += w;
            float4 v0 = vs[n][0], v1 = vs[n][1], v2 = vs[n][2], v3 = vs[n][3];
            o[0]  += w*v0.x; o[1]  += w*v0.y; o[2]  += w*v0.z; o[3]  += w*v0.w;
            o[4]  += w*v1.x; o[5]  += w*v1.y; o[6]  += w*v1.z; o[7]  += w*v1.w;
            o[8]  += w*v2.x; o[9]  += w*v2.y; o[10] += w*v2.z; o[11] += w*v2.w;
            o[12] += w*v3.x; o[13] += w*v3.y; o[14] += w*v3.z; o[15] += w*v3.w;
        }
    }

    float inv_l = 1.f / l;
    float4* out4 = (float4*)out;
    size_t ob = (size_t)(b * P + p) * 32 + h * 4;
    #pragma unroll
    for (int c = 0; c < 4; ++c)
        out4[ob + c] = make_float4(o[c*4]*inv_l, o[c*4+1]*inv_l,
                                   o[c*4+2]*inv_l, o[c*4+3]*inv_l);
}

// ---------------------------------------------------------------------------
// Pointer scores + logits (R8 version, restored): sc = mh[b] @ nodes[b]^T,
// fused tanh/bias/mask. Double-LDS GEMM: 64x64 tile, K in 2 steps of 64,
// both operand tiles staged in LDS. Thread tile 4x4 interleaved (stride 16).
// ---------------------------------------------------------------------------
__global__ __launch_bounds__(256) void pointer_kernel(
    const float* __restrict__ mh, const float* __restrict__ nodes,
    const float* __restrict__ mask, const int* __restrict__ gid,
    const int* __restrict__ cmp, const float* __restrict__ btab,
    float* __restrict__ out)
{
    __shared__ float4 as[64][17];     // mh tile:    64 p-rows x 64 k (pad 17)
    __shared__ float4 bs[64][17];     // nodes tile: 64 n-rows x 64 k (pad 17)
    const int b = blockIdx.z;
    const int p_base = blockIdx.y * 64;
    const int n_base = blockIdx.x * 64;
    const int tid = threadIdx.x;
    const int pi = tid >> 4;          // 0..15
    const int ni = tid & 15;          // 0..15

    const float4* mh4 = (const float4*)mh;
    const float4* nodes4 = (const float4*)nodes;

    float acc[4][4];
    #pragma unroll
    for (int i = 0; i < 4; ++i)
        #pragma unroll
        for (int j = 0; j < 4; ++j) acc[i][j] = 0.f;

    for (int ks = 0; ks < 2; ++ks) {
        if (ks) __syncthreads();
        #pragma unroll
        for (int t = 0; t < 4; ++t) {
            int idx = tid + 256 * t;
            int r = idx >> 4, c = idx & 15;
            int pr = p_base + r; pr = pr < P ? pr : P - 1;
            int nr = n_base + r; nr = nr < N ? nr : N - 1;
            as[r][c] = mh4[(size_t)(b * P + pr) * 32 + ks * 16 + c];
            bs[r][c] = nodes4[(size_t)(b * N + nr) * 32 + ks * 16 + c];
        }
        __syncthreads();

        for (int c4 = 0; c4 < 16; ++c4) {
            float4 a[4], w[4];
            #pragma unroll
            for (int i = 0; i < 4; ++i) a[i] = as[pi + 16 * i][c4];
            #pragma unroll
            for (int j = 0; j < 4; ++j) w[j] = bs[ni + 16 * j][c4];
            #pragma unroll
            for (int i = 0; i < 4; ++i)
                #pragma unroll
                for (int j = 0; j < 4; ++j)
                    acc[i][j] += dot4(a[i], w[j]);
        }
    }

    float bt[MAX_DELTA + 1];
    #pragma unroll
    for (int t = 0; t <= MAX_DELTA; ++t) bt[t] = btab[t];

    #pragma unroll
    for (int i = 0; i < 4; ++i) {
        int p = p_base + pi + 16 * i;
        if (p >= P) continue;
        int cm = cmp[b * P + p];
        #pragma unroll
        for (int j = 0; j < 4; ++j) {
            int n = n_base + ni + 16 * j;
            if (n >= N) continue;
            int g = gid[b * N + n];
            int delta = g - cm;
            delta = delta < 0 ? 0 : (delta > MAX_DELTA ? MAX_DELTA : delta);
            float mv = mask[(size_t)(b * P + p) * N + n];
            float pb = isfinite(mv) ? bt[delta] : 0.f;
            float logit = LOGIT_CLIP * tanhf(acc[i][j] * INV_SQRT_E) + pb + mv;
            out[(size_t)(b * P + p) * N + n] = logit;
        }
    }
}

// ---------------------------------------------------------------------------
// Top-k (k=20) + temperature + renormalize, in place on d_out (R8 version).
// One wave per row; radix-select via ballot, exact jax.lax.top_k tie-break.
// ---------------------------------------------------------------------------
__global__ __launch_bounds__(256) void topk_kernel(float* __restrict__ io)
{
    const int wv = threadIdx.x >> 6, lane = threadIdx.x & 63;
    const long row = (long)blockIdx.x * 4 + wv;
    float* r = io + row * N;

    float x[4];
    unsigned u[4];
    #pragma unroll
    for (int j = 0; j < 4; ++j) {
        int n = lane + 64 * j;
        bool valid = n < N;
        x[j] = valid ? r[n] : -INFINITY;
        unsigned bb = __float_as_uint(x[j]);
        u[j] = valid ? ((bb & 0x80000000u) ? ~bb : (bb | 0x80000000u)) : 0u;
    }

    unsigned p = 0;
    for (int i = 31; i >= 0; --i) {
        unsigned c = p | (1u << i);
        int cnt = 0;
        #pragma unroll
        for (int j = 0; j < 4; ++j)
            cnt += (int)__popcll(__ballot(u[j] >= c));
        if (cnt >= TOP_K) p = c;
    }

    int cnt_gt = 0;
    #pragma unroll
    for (int j = 0; j < 4; ++j)
        cnt_gt += (int)__popcll(__ballot(u[j] > p));
    const int needed = TOP_K - cnt_gt;

    const unsigned long long lt_mask = (1ull << lane) - 1ull;
    bool sel[4];
    int eq_before = 0;
    #pragma unroll
    for (int j = 0; j < 4; ++j) {
        unsigned long long em = __ballot(u[j] == p);
        int myrank = eq_before + (int)__popcll(em & lt_mask);
        sel[j] = (u[j] > p) || ((u[j] == p) && (myrank < needed));
        eq_before += (int)__popcll(em);
    }

    unsigned tb = (p & 0x80000000u) ? (p & 0x7FFFFFFFu) : ~p;
    float Tf = __uint_as_float(tb);

    float e[4];
    float sum = 0.f;
    if (isfinite(Tf)) {
        #pragma unroll
        for (int j = 0; j < 4; ++j) {
            e[j] = sel[j] ? __expf((x[j] - Tf) * INV_TEMP) : 0.f;
            sum += e[j];
        }
    } else {
        #pragma unroll
        for (int j = 0; j < 4; ++j) {
            e[j] = sel[j] ? 1.f : 0.f;
            sum += e[j];
        }
    }
    #pragma unroll
    for (int off = 32; off > 0; off >>= 1) sum += __shfl_xor(sum, off);
    float inv = 1.f / sum;
    #pragma unroll
    for (int j = 0; j < 4; ++j) {
        int n = lane + 64 * j;
        if (n < N) r[n] = e[j] * inv;
    }
}

// ---------------------------------------------------------------------------
extern "C" void kernel_launch(void* const* d_in, const int* in_sizes, int n_in,
                              void* d_out, int out_size, void* d_ws, size_t ws_size,
                              hipStream_t stream) {
    const float* nodes = (const float*)d_in[0];
    const float* first = (const float*)d_in[1];
    const float* last  = (const float*)d_in[2];
    const float* mask  = (const float*)d_in[3];
    const int*   gid   = (const int*)d_in[4];
    const int*   cmp   = (const int*)d_in[5];
    const float* Wqf   = (const float*)d_in[6];
    const float* Wql   = (const float*)d_in[7];
    const float* Wk    = (const float*)d_in[8];
    const float* Wv    = (const float*)d_in[9];
    const float* Wc    = (const float*)d_in[10];
    const float* bc    = (const float*)d_in[11];
    const float* btab  = (const float*)d_in[12];
    float* out = (float*)d_out;

    float* ws   = (float*)d_ws;
    const size_t SLOT = (size_t)B * P * E;   // 6,553,600 floats
    float* qb  = ws;                 // q, later reused for mh
    float* kb  = ws + SLOT;
    float* vb  = ws + 2 * SLOT;
    float* ao  = ws + 3 * SLOT;      // attention output (concat heads)

    const int M = B * P;             // 51200 rows (= B*N too)

    // q, k, v in one dispatch (blocks 0..1599 -> q, 1600..3199 -> k/v)
    qkv_proj_kernel<<<2 * (M / 32), 256, 0, stream>>>(
        first, Wqf, last, Wql, qb, nodes, Wk, Wv, kb, vb);

    // masked MHA (bound-softmax single pass, XCD-aware remap)
    attn_kernel<<<B * H, 256, 0, stream>>>(qb, kb, vb, mask, ao);

    // mh = ao @ Wc + bc   (into q's slot — q is dead now)
    proj_kernel<<<M / 32, 256, 0, stream>>>(ao, Wc, nullptr, nullptr, bc, qb);

    // pointer logits into d_out (double-LDS GEMM)
    dim3 pgrid((N + 63) / 64, (P + 63) / 64, B);
    pointer_kernel<<<pgrid, 256, 0, stream>>>(qb, nodes, mask, gid, cmp, btab, out);

    // top-k + renormalize in place
    topk_kernel<<<(B * P) / 4, 256, 0, stream>>>(out);
}